// Round 4
// baseline (1477464.062 us; speedup 1.0000x reference)
//
#include <hip/hip_runtime.h>
#include <hip/hip_bf16.h>

typedef unsigned short u16;
typedef unsigned int u32;
typedef unsigned long long u64;

#define HD 512
#define BATCH 128
#define TENC 512
#define WPAD 520   // LDS row stride in bf16 elems (even -> u32-aligned rows)

typedef float f32x4 __attribute__((ext_vector_type(4)));
typedef short s16x8 __attribute__((ext_vector_type(8)));

__device__ __forceinline__ u16 f2b(float f) {
    u32 u = __float_as_uint(f);
    u32 r = (u + 0x7FFFu + ((u >> 16) & 1u)) >> 16;   // RNE
    return (u16)r;
}
__device__ __forceinline__ float b2f(u16 h) {
    return __uint_as_float(((u32)h) << 16);
}
__device__ __forceinline__ float sigm(float z) { return 1.0f / (1.0f + __expf(-z)); }
__device__ __forceinline__ float tanh_f(float z) { return 1.0f - 2.0f / (__expf(2.0f * z) + 1.0f); }

// sc0 load (bypass L1 only; served by the XCD-shared L2). 64-bit vaddr form.
__device__ __forceinline__ u32 ld_sc0(const u32* p) {
    u32 v;
    asm volatile("global_load_dword %0, %1, off sc0\n\ts_waitcnt vmcnt(0)"
                 : "=&v"(v) : "v"((u64)p) : "memory");
    return v;
}

// 8 parallel tagged-word loads through the XCD-shared L2 (sc0 only).
// vaddr (VGPR-pair) form; +4096 bias so each pair covers two 4KB planes
// via offset -4096 / 0 (13-bit signed imm cannot encode +4096).
__device__ __forceinline__ void ld8_l2(u64 a0, u64 a1, u64 a2, u64 a3,
                                       u64& w0, u64& w1, u64& w2, u64& w3,
                                       u64& w4, u64& w5, u64& w6, u64& w7) {
    asm volatile(
        "global_load_dwordx2 %0, %8, off offset:-4096 sc0\n\t"
        "global_load_dwordx2 %1, %8, off sc0\n\t"
        "global_load_dwordx2 %2, %9, off offset:-4096 sc0\n\t"
        "global_load_dwordx2 %3, %9, off sc0\n\t"
        "global_load_dwordx2 %4, %10, off offset:-4096 sc0\n\t"
        "global_load_dwordx2 %5, %10, off sc0\n\t"
        "global_load_dwordx2 %6, %11, off offset:-4096 sc0\n\t"
        "global_load_dwordx2 %7, %11, off sc0\n\t"
        "s_waitcnt vmcnt(0)"
        : "=&v"(w0), "=&v"(w1), "=&v"(w2), "=&v"(w3),
          "=&v"(w4), "=&v"(w5), "=&v"(w6), "=&v"(w7)
        : "v"(a0), "v"(a1), "v"(a2), "v"(a3)
        : "memory");
}

// ---------------------------------------------------------------------------
// init: seed tagged h-buffer (parity0 = h0 with tag 0), zero probe/vote area,
// build rnn_Whh transposed bf16 [k][j].
// ---------------------------------------------------------------------------
__global__ void init_misc(const float* __restrict__ h0, const float* __restrict__ rWhh,
                          u64* __restrict__ hb64, u16* __restrict__ rT,
                          u32* __restrict__ xf) {
    int idx = blockIdx.x * 256 + threadIdx.x;      // 512 blocks x 256 = 131072
    if (idx < 1024) xf[idx] = 0u;                   // votes + probe words
    if (idx < 65536) {                              // 8 g x 2 parity x 4096 words
        int g   = idx >> 13;
        int r   = idx & 8191;
        int p   = r >> 12;
        int ofs = r & 4095;
        int b   = ofs >> 8, jp = ofs & 255;
        u64 v = 0ull;                               // tag 0
        if (p == 0) {
            const float* hrow = h0 + (size_t)(g * 16 + b) * HD + jp * 2;
            u32 lo = (u32)f2b(hrow[0]) | ((u32)f2b(hrow[1]) << 16);
            v = (u64)lo;                            // tag 0 for h_0
        }
        hb64[(size_t)(g * 2 + p) * 4096 + b * 256 + jp] = v;
    }
    for (int i = idx; i < 262144; i += 131072) {    // rT[k*512+j] = rWhh[j][k]
        int k = i >> 9, j = i & 511;
        rT[i] = f2b(rWhh[j * 512 + k]);
    }
}

// ---------------------------------------------------------------------------
// Encoder LSTM: 8 batch-groups x 16 wgs. Tagged 8B handoff words.
// Placement test (SOUND): every block reads HW_REG_XCC_ID (m09-verified on
// MI355X) and votes {probe_seen, xcc}. Fast path (plain stores + sc0 polls
// through the shared XCD L2, ~200cy RT) requires ALL 16 xcc ids equal AND
// all 16 saw the plain-store probe. Either check failing -> agent-scope LLC
// path (round-1 proven). Fast poll carries a watchdog so an unforeseen
// visibility break fails the bench instead of hanging the harness.
// ---------------------------------------------------------------------------
__global__ __launch_bounds__(512, 2) void enc_lstm(
    const float* __restrict__ xseq, const float* __restrict__ c0,
    const float* __restrict__ Wih, const float* __restrict__ Whh,
    const float* __restrict__ bih, const float* __restrict__ bhh,
    u16* __restrict__ enc, u64* __restrict__ hb64, u32* __restrict__ xf) {

    __shared__ u16 hlds[16 * WPAD];     // 16640 B: staged h tile [16b][512k] bf16
    __shared__ float exg[16 * 132];     // 8448 B: gate pre-activations [b][128 rows]
    __shared__ float bias_l[128];
    __shared__ float wih_l[128];
    __shared__ u32 fastsh;

    const int tid = threadIdx.x;
    const int g = blockIdx.x & 7;       // batch group
    const int sl = blockIdx.x >> 3;     // hidden slot 0..15

    // mechanism probe store ASAP (visibility hides under weight hoist)
    if (sl == 0 && tid == 0)
        __hip_atomic_store(&xf[128 + g * 16], 0xACEDu,
                           __ATOMIC_RELAXED, __HIP_MEMORY_SCOPE_WORKGROUP);

    u32 myxcc;
    asm volatile("s_getreg_b32 %0, hwreg(HW_REG_XCC_ID)" : "=s"(myxcc));
    myxcc &= 15u;

    if (tid < 128) {
        int n = (tid >> 5) * 512 + sl * 32 + (tid & 31);
        bias_l[tid] = bih[n] + bhh[n];
        wih_l[tid] = Wih[n];
    }

    const int bT = tid >> 5, jl = tid & 31;               // cell-update mapping
    float c = c0[(g * 16 + bT) * HD + sl * 32 + jl];      // persistent cell state

    const int lane = tid & 63, wv = tid >> 6;
    const int q = lane >> 4, cl = lane & 15;
    const int R = (wv >> 1) * 32 + (wv & 1) * 16;         // wave's 16 gate-rows

    // hoist this lane's 16 B-fragments of Whh into registers (64 VGPRs)
    s16x8 bw[16];
    {
        int r = R + cl;
        int grow = (r >> 5) * 512 + sl * 32 + (r & 31);
        const float* wrow = Whh + (size_t)grow * 512;
        #pragma unroll
        for (int ks = 0; ks < 16; ++ks) {
            s16x8 v;
            #pragma unroll
            for (int j = 0; j < 8; ++j)
                v[j] = (short)f2b(wrow[ks * 32 + q * 8 + j]);
            bw[ks] = v;
        }
    }

    // ---- vote: {probe_seen, xcc}; decide fast iff all-equal-xcc AND all-seen
    const u32 myvote = 0u;  // placeholder to keep reg names obvious
    (void)myvote;
    if (tid == 0) {
        u32 seen = 0;
        for (int it = 0; it < 1024; ++it) {
            if (ld_sc0(&xf[128 + g * 16]) == 0xACEDu) { seen = 1; break; }
        }
        u32 v = ((seen ? 1u : 2u) << 8) | (myxcc + 1u);
        __hip_atomic_store(&xf[g * 16 + sl], v,
                           __ATOMIC_RELAXED, __HIP_MEMORY_SCOPE_AGENT);
    }
    if (tid < 16) {
        u32 v;
        while ((v = __hip_atomic_load(&xf[g * 16 + tid], __ATOMIC_RELAXED,
                                      __HIP_MEMORY_SCOPE_AGENT)) == 0u)
            __builtin_amdgcn_s_sleep(1);
        bool good = ((v >> 8) == 1u) && ((v & 0xFFu) == (myxcc + 1u));
        u64 bal = __ballot(good);
        if (tid == 0) fastsh = ((bal & 0xFFFFull) == 0xFFFFull) ? 1u : 0u;
    }

    u32* hlds32 = (u32*)hlds;
    __syncthreads();
    const bool fast = (fastsh != 0u);

    // byte base for this thread's 8 tagged words (+4096 bias for ld8_l2)
    const u64 abase0 = (u64)hb64 + (u64)g * 65536u + (u64)tid * 8u + 4096u;

    for (int t = 0; t < TENC; ++t) {
        const u64* src = hb64 + (size_t)(g * 2 + (t & 1)) * 4096;
        const u32 want = (u32)t;
        float xv = xseq[t * BATCH + g * 16 + bT];   // prefetched; used post-MFMA

        if (fast) {
            u64 a0 = abase0 + (u64)((t & 1) << 15);
            u64 w0, w1, w2, w3, w4, w5, w6, w7;
            ld8_l2(a0, a0 + 8192u, a0 + 16384u, a0 + 24576u,
                   w0, w1, w2, w3, w4, w5, w6, w7);
            int guard = 0;
            for (;;) {
                bool ok = ((u32)(w0 >> 32) == want) & ((u32)(w1 >> 32) == want) &
                          ((u32)(w2 >> 32) == want) & ((u32)(w3 >> 32) == want) &
                          ((u32)(w4 >> 32) == want) & ((u32)(w5 >> 32) == want) &
                          ((u32)(w6 >> 32) == want) & ((u32)(w7 >> 32) == want);
                if (ok || ++guard > 8192) break;   // watchdog: fail, don't hang
                ld8_l2(a0, a0 + 8192u, a0 + 16384u, a0 + 24576u,
                       w0, w1, w2, w3, w4, w5, w6, w7);
            }
            int b0 = tid >> 8, wq = tid & 255;
            hlds32[(b0     ) * 260 + wq] = (u32)w0;
            hlds32[(b0 +  2) * 260 + wq] = (u32)w1;
            hlds32[(b0 +  4) * 260 + wq] = (u32)w2;
            hlds32[(b0 +  6) * 260 + wq] = (u32)w3;
            hlds32[(b0 +  8) * 260 + wq] = (u32)w4;
            hlds32[(b0 + 10) * 260 + wq] = (u32)w5;
            hlds32[(b0 + 12) * 260 + wq] = (u32)w6;
            hlds32[(b0 + 14) * 260 + wq] = (u32)w7;
        } else {
            u64 vv[8];
            #pragma unroll
            for (int i = 0; i < 8; ++i)
                vv[i] = __hip_atomic_load(src + tid + i * 512, __ATOMIC_RELAXED,
                                          __HIP_MEMORY_SCOPE_AGENT);
            for (;;) {
                bool ok = true;
                #pragma unroll
                for (int i = 0; i < 8; ++i) {
                    if ((u32)(vv[i] >> 32) != want) {
                        ok = false;
                        vv[i] = __hip_atomic_load(src + tid + i * 512, __ATOMIC_RELAXED,
                                                  __HIP_MEMORY_SCOPE_AGENT);
                    }
                }
                if (ok) break;
            }
            #pragma unroll
            for (int i = 0; i < 8; ++i) {
                int idx = tid + i * 512;
                hlds32[(idx >> 8) * 260 + (idx & 255)] = (u32)vv[i];
            }
        }
        __syncthreads();                            // S1: hlds ready

        // dual accumulators: halve the dependent MFMA chain
        f32x4 acc0 = {0.f, 0.f, 0.f, 0.f}, acc1 = {0.f, 0.f, 0.f, 0.f};
        #pragma unroll
        for (int ks = 0; ks < 16; ks += 2) {
            s16x8 av0 = *(const s16x8*)&hlds[cl * WPAD + ks * 32 + q * 8];
            s16x8 av1 = *(const s16x8*)&hlds[cl * WPAD + (ks + 1) * 32 + q * 8];
            acc0 = __builtin_amdgcn_mfma_f32_16x16x32_bf16(av0, bw[ks], acc0, 0, 0, 0);
            acc1 = __builtin_amdgcn_mfma_f32_16x16x32_bf16(av1, bw[ks + 1], acc1, 0, 0, 0);
        }
        f32x4 acc = acc0 + acc1;
        #pragma unroll
        for (int r4 = 0; r4 < 4; ++r4)
            exg[(q * 4 + r4) * 132 + R + cl] = acc[r4];   // D: row m=q*4+r4, col n=cl
        __syncthreads();                            // S2: exg ready + hlds reads done

        // LSTM cell for (bT, jl)
        const float* exb = &exg[bT * 132];
        float gi = exb[jl]      + xv * wih_l[jl]      + bias_l[jl];
        float gf = exb[32 + jl] + xv * wih_l[32 + jl] + bias_l[32 + jl];
        float gg = exb[64 + jl] + xv * wih_l[64 + jl] + bias_l[64 + jl];
        float go = exb[96 + jl] + xv * wih_l[96 + jl] + bias_l[96 + jl];
        c = sigm(gf) * c + sigm(gi) * tanh_f(gg);
        float hv = sigm(go) * tanh_f(c);
        u16 h16 = f2b(hv);
        int jgl = sl * 32 + jl;

        // tagged h_{t+1} store: pair + tag in ONE 8B store (critical path)
        u32 me = (u32)h16;
        u32 up = (u32)__shfl_down((int)me, 1, 64);
        if ((jl & 1) == 0) {
            u64 word = (u64)(me | (up << 16)) | ((u64)(u32)(t + 1) << 32);
            u64* dst = hb64 + (size_t)(g * 2 + ((t + 1) & 1)) * 4096
                            + bT * 256 + (jgl >> 1);
            if (fast)   // plain store: write-through into the shared XCD L2
                __hip_atomic_store(dst, word, __ATOMIC_RELAXED,
                                   __HIP_MEMORY_SCOPE_WORKGROUP);
            else
                __hip_atomic_store(dst, word, __ATOMIC_RELAXED,
                                   __HIP_MEMORY_SCOPE_AGENT);
        }
        // enc write AFTER the handoff store: off the critical path
        enc[((size_t)t * BATCH + g * 16 + bT) * HD + jgl] = h16;
    }
}

// ---------------------------------------------------------------------------
// Fused decoder: one wg per batch row, 32 steps. p2 uses a TRUE 2-deep
// dual-buffer pipeline (2x unrolled blocks, 128B/wave in flight).
// ---------------------------------------------------------------------------
__global__ __launch_bounds__(512, 2) void dec_all(
    const float* __restrict__ xlast, const u16* __restrict__ enc,
    const u16* __restrict__ rT, const float* __restrict__ rWih,
    const float* __restrict__ rbih, const float* __restrict__ rbhh,
    const float* __restrict__ linW, const float* __restrict__ linb,
    float* __restrict__ dout) {

    __shared__ float hp[512];          // h entering the step
    __shared__ float ctxl[8 * 512];    // p1 partials, then p2 ctx partials
    __shared__ float red[512];         // hn broadcast, then reduce slots
    __shared__ float mw[8], lw[8];
    __shared__ float xsh;

    const int tid = threadIdx.x;
    const int b = blockIdx.x;
    const int wv = tid >> 6, lane = tid & 63;

    hp[tid] = b2f(enc[(size_t)511 * BATCH * HD + b * HD + tid]);  // h_enc
    float x = xlast[b];
    const float bia = rbih[tid] + rbhh[tid];
    const float wih = rWih[tid];
    const float lwt = linW[tid];
    const float lb = linb[0];
    const uint4* rT4 = (const uint4*)rT;                 // [512 k][64 chunks]
    const u16* ebase = enc + (size_t)b * HD + lane * 8;  // t-stride = 65536 elems
    __syncthreads();

    for (int s = 0; s < 32; ++s) {
        // preload blocks 0 and 1 (hides under p1)
        uint4 bufA[4], bufB[4];
        #pragma unroll
        for (int i = 0; i < 4; ++i) {
            bufA[i] = *(const uint4*)(ebase + (size_t)(i * 8 + wv) * 65536);
            bufB[i] = *(const uint4*)(ebase + (size_t)(32 + i * 8 + wv) * 65536);
        }

        // ---- phase 1: wave wv covers k in [wv*64, wv*64+64)
        float pa[8] = {0, 0, 0, 0, 0, 0, 0, 0};
        const uint4* base = rT4 + (size_t)(wv * 64) * 64 + lane;
        #pragma unroll 4
        for (int kk = 0; kk < 64; ++kk) {
            float hk = hp[wv * 64 + kk];
            uint4 w = base[kk * 64];
            pa[0] = fmaf(hk, b2f((u16)(w.x & 0xFFFF)), pa[0]);
            pa[1] = fmaf(hk, b2f((u16)(w.x >> 16)),    pa[1]);
            pa[2] = fmaf(hk, b2f((u16)(w.y & 0xFFFF)), pa[2]);
            pa[3] = fmaf(hk, b2f((u16)(w.y >> 16)),    pa[3]);
            pa[4] = fmaf(hk, b2f((u16)(w.z & 0xFFFF)), pa[4]);
            pa[5] = fmaf(hk, b2f((u16)(w.z >> 16)),    pa[5]);
            pa[6] = fmaf(hk, b2f((u16)(w.w & 0xFFFF)), pa[6]);
            pa[7] = fmaf(hk, b2f((u16)(w.w >> 16)),    pa[7]);
        }
        #pragma unroll
        for (int i = 0; i < 8; ++i) ctxl[wv * 512 + lane * 8 + i] = pa[i];
        __syncthreads();

        float a = bia + x * wih;
        #pragma unroll
        for (int i = 0; i < 8; ++i) a += ctxl[i * 512 + tid];
        float hv = tanh_f(a);
        red[tid] = hv;                  // hn broadcast
        __syncthreads();

        // ---- phase 2: wave wv handles t = blk*32 + i*8 + wv
        float h8[8];
        #pragma unroll
        for (int i = 0; i < 8; ++i) h8[i] = red[lane * 8 + i];
        float m = -1e30f, l = 0.f;
        float acc[8] = {0, 0, 0, 0, 0, 0, 0, 0};

        auto proc4 = [&](const uint4* bf) {
            #pragma unroll
            for (int i = 0; i < 4; ++i) {
                uint4 ev = bf[i];
                float e[8];
                e[0] = b2f((u16)(ev.x & 0xFFFF)); e[1] = b2f((u16)(ev.x >> 16));
                e[2] = b2f((u16)(ev.y & 0xFFFF)); e[3] = b2f((u16)(ev.y >> 16));
                e[4] = b2f((u16)(ev.z & 0xFFFF)); e[5] = b2f((u16)(ev.z >> 16));
                e[6] = b2f((u16)(ev.w & 0xFFFF)); e[7] = b2f((u16)(ev.w >> 16));
                float sp = 0.f;
                #pragma unroll
                for (int j = 0; j < 8; ++j) sp = fmaf(e[j], h8[j], sp);
                #pragma unroll
                for (int mk = 1; mk < 64; mk <<= 1) sp += __shfl_xor(sp, mk, 64);
                if (sp > m) {
                    float sc = __expf(m - sp);
                    l *= sc;
                    #pragma unroll
                    for (int j = 0; j < 8; ++j) acc[j] *= sc;
                    m = sp;
                }
                float p = __expf(sp - m);
                l += p;
                #pragma unroll
                for (int j = 0; j < 8; ++j) acc[j] = fmaf(p, e[j], acc[j]);
            }
        };

        for (int bb = 0; bb < 16; bb += 2) {
            uint4 nA[4], nB[4];
            if (bb < 14) {
                #pragma unroll
                for (int i = 0; i < 4; ++i) {
                    nA[i] = *(const uint4*)(ebase +
                              (size_t)((bb + 2) * 32 + i * 8 + wv) * 65536);
                    nB[i] = *(const uint4*)(ebase +
                              (size_t)((bb + 3) * 32 + i * 8 + wv) * 65536);
                }
            }
            proc4(bufA);
            proc4(bufB);
            if (bb < 14) {
                #pragma unroll
                for (int i = 0; i < 4; ++i) { bufA[i] = nA[i]; bufB[i] = nB[i]; }
            }
        }
        if (lane == 0) { mw[wv] = m; lw[wv] = l; }
        #pragma unroll
        for (int i = 0; i < 8; ++i) ctxl[wv * HD + lane * 8 + i] = acc[i];
        __syncthreads();

        // ---- phase 3: merge online-softmax states, project, relu
        float M = mw[0];
        #pragma unroll
        for (int i = 1; i < 8; ++i) M = fmaxf(M, mw[i]);
        float L = 0.f, aw[8];
        #pragma unroll
        for (int i = 0; i < 8; ++i) { aw[i] = __expf(mw[i] - M); L += aw[i] * lw[i]; }
        float cj = 0.f;
        #pragma unroll
        for (int i = 0; i < 8; ++i) cj = fmaf(aw[i], ctxl[i * HD + tid], cj);
        float r = cj * lwt;
        #pragma unroll
        for (int mk = 1; mk < 64; mk <<= 1) r += __shfl_xor(r, mk, 64);
        if (lane == 0) red[wv] = r;
        __syncthreads();
        if (tid == 0) {
            float o = (red[0] + red[1] + red[2] + red[3] +
                       red[4] + red[5] + red[6] + red[7]) / L + lb;
            o = fmaxf(o, 0.f);
            dout[s * BATCH + b] = o;
            xsh = o;
        }
        __syncthreads();
        x = xsh;
        hp[tid] = hv;                   // h for next step
        __syncthreads();
    }
}

// ---------------------------------------------------------------------------
extern "C" void kernel_launch(void* const* d_in, const int* in_sizes, int n_in,
                              void* d_out, int out_size, void* d_ws, size_t ws_size,
                              hipStream_t stream) {
    const float* xseq = (const float*)d_in[0];   // [513,128,1]
    const float* h0   = (const float*)d_in[1];
    const float* c0   = (const float*)d_in[2];
    const float* Wih  = (const float*)d_in[3];   // [2048,1]
    const float* Whh  = (const float*)d_in[4];   // [2048,512]
    const float* bih  = (const float*)d_in[5];
    const float* bhh  = (const float*)d_in[6];
    const float* rWih = (const float*)d_in[7];   // [512,1]
    const float* rWhh = (const float*)d_in[8];   // [512,512]
    const float* rbih = (const float*)d_in[9];
    const float* rbhh = (const float*)d_in[10];
    const float* linW = (const float*)d_in[11];  // [1,512]
    const float* linb = (const float*)d_in[12];
    float* dout = (float*)d_out;                 // [32,128,1]

    // workspace layout
    char* ws = (char*)d_ws;
    u16* enc  = (u16*)ws;                                  // 64 MB
    u16* rT   = (u16*)(ws + 67108864);                     // 512 KB
    u64* hb64 = (u64*)(ws + 67108864 + 524288);            // 512 KB tagged h
    u32* xf   = (u32*)(ws + 67108864 + 1048576);           // 4 KB probe/votes

    init_misc<<<512, 256, 0, stream>>>(h0, rWhh, hb64, rT, xf);
    enc_lstm<<<128, 512, 0, stream>>>(xseq, c0, Wih, Whh, bih, bhh, enc, hb64, xf);
    dec_all<<<128, 512, 0, stream>>>(xseq + 512 * BATCH, enc, rT, rWih,
                                     rbih, rbhh, linW, linb, dout);
}

// Round 5
// 3268.066 us; speedup vs baseline: 452.0913x; 452.0913x over previous
//
#include <hip/hip_runtime.h>
#include <hip/hip_bf16.h>

typedef unsigned short u16;
typedef unsigned int u32;
typedef unsigned long long u64;

#define HD 512
#define BATCH 128
#define TENC 512
#define WPAD 520   // LDS row stride in bf16 elems (even -> u32-aligned rows)

typedef float f32x4 __attribute__((ext_vector_type(4)));
typedef short s16x8 __attribute__((ext_vector_type(8)));

__device__ __forceinline__ u16 f2b(float f) {
    u32 u = __float_as_uint(f);
    u32 r = (u + 0x7FFFu + ((u >> 16) & 1u)) >> 16;   // RNE
    return (u16)r;
}
__device__ __forceinline__ float b2f(u16 h) {
    return __uint_as_float(((u32)h) << 16);
}
__device__ __forceinline__ float sigm(float z) { return 1.0f / (1.0f + __expf(-z)); }
__device__ __forceinline__ float tanh_f(float z) { return 1.0f - 2.0f / (__expf(2.0f * z) + 1.0f); }

// sc0 store: write-through L1 INTO the XCD-shared L2 (not LLC). The round-4
// failure mode (correct-but-1000x-slow) showed plain stores do NOT promptly
// reach L2; sc0 on the store is the missing half of the L2 handoff.
__device__ __forceinline__ void st_sc0(u64* p, u64 v) {
    asm volatile("global_store_dwordx2 %0, %1, off sc0"
                 :: "v"((u64)p), "v"(v) : "memory");
}

// 8 parallel tagged-word loads through the XCD-shared L2 (sc0: bypass L1).
// vaddr (VGPR-pair) form; +4096 bias so each pair covers two 4KB planes
// via offset -4096 / 0 (13-bit signed imm cannot encode +4096).
__device__ __forceinline__ void ld8_l2(u64 a0, u64 a1, u64 a2, u64 a3,
                                       u64& w0, u64& w1, u64& w2, u64& w3,
                                       u64& w4, u64& w5, u64& w6, u64& w7) {
    asm volatile(
        "global_load_dwordx2 %0, %8, off offset:-4096 sc0\n\t"
        "global_load_dwordx2 %1, %8, off sc0\n\t"
        "global_load_dwordx2 %2, %9, off offset:-4096 sc0\n\t"
        "global_load_dwordx2 %3, %9, off sc0\n\t"
        "global_load_dwordx2 %4, %10, off offset:-4096 sc0\n\t"
        "global_load_dwordx2 %5, %10, off sc0\n\t"
        "global_load_dwordx2 %6, %11, off offset:-4096 sc0\n\t"
        "global_load_dwordx2 %7, %11, off sc0\n\t"
        "s_waitcnt vmcnt(0)"
        : "=&v"(w0), "=&v"(w1), "=&v"(w2), "=&v"(w3),
          "=&v"(w4), "=&v"(w5), "=&v"(w6), "=&v"(w7)
        : "v"(a0), "v"(a1), "v"(a2), "v"(a3)
        : "memory");
}

// ---------------------------------------------------------------------------
// init: seed tagged h-buffer (parity0 = h0 with tag 0), zero vote area,
// build rnn_Whh transposed bf16 [k][j].
// ---------------------------------------------------------------------------
__global__ void init_misc(const float* __restrict__ h0, const float* __restrict__ rWhh,
                          u64* __restrict__ hb64, u16* __restrict__ rT,
                          u32* __restrict__ xf) {
    int idx = blockIdx.x * 256 + threadIdx.x;      // 512 blocks x 256 = 131072
    if (idx < 1024) xf[idx] = 0u;                   // vote words
    if (idx < 65536) {                              // 8 g x 2 parity x 4096 words
        int g   = idx >> 13;
        int r   = idx & 8191;
        int p   = r >> 12;
        int ofs = r & 4095;
        int b   = ofs >> 8, jp = ofs & 255;
        u64 v = 0ull;                               // tag 0
        if (p == 0) {
            const float* hrow = h0 + (size_t)(g * 16 + b) * HD + jp * 2;
            u32 lo = (u32)f2b(hrow[0]) | ((u32)f2b(hrow[1]) << 16);
            v = (u64)lo;                            // tag 0 for h_0
        }
        hb64[(size_t)(g * 2 + p) * 4096 + b * 256 + jp] = v;
    }
    for (int i = idx; i < 262144; i += 131072) {    // rT[k*512+j] = rWhh[j][k]
        int k = i >> 9, j = i & 511;
        rT[i] = f2b(rWhh[j * 512 + k]);
    }
}

// ---------------------------------------------------------------------------
// Encoder LSTM: 8 batch-groups x 16 wgs. Tagged 8B handoff words.
// Fast path: sc0 stores + sc0 polls through the shared XCD L2 (gated by
// all-16-equal HW_REG_XCC_ID). SOUND RECOVERY: polls are bounded; on any
// timeout the whole wg (after a barrier) re-stores its last TWO steps'
// words agent-scope (max skew between wgs is 1 step, so two planes cover
// every waiter), flips permanently to the proven agent path, and re-polls
// agent-scope. No stale reads, no hangs, worst case ~= round-1 perf.
// ---------------------------------------------------------------------------
__global__ __launch_bounds__(512, 2) void enc_lstm(
    const float* __restrict__ xseq, const float* __restrict__ c0,
    const float* __restrict__ Wih, const float* __restrict__ Whh,
    const float* __restrict__ bih, const float* __restrict__ bhh,
    u16* __restrict__ enc, u64* __restrict__ hb64, u32* __restrict__ xf) {

    __shared__ u16 hlds[16 * WPAD];     // 16640 B: staged h tile [16b][512k] bf16
    __shared__ float exg[16 * 132];     // 8448 B: gate pre-activations [b][128 rows]
    __shared__ float bias_l[128];
    __shared__ float wih_l[128];
    __shared__ u32 modesh;              // 0 = fast (XCD L2), 1 = slow (agent/LLC)
    __shared__ u32 toutsh;              // timeout seen this step

    const int tid = threadIdx.x;
    const int g = blockIdx.x & 7;       // batch group
    const int sl = blockIdx.x >> 3;     // hidden slot 0..15

    u32 myxcc;
    asm volatile("s_getreg_b32 %0, hwreg(HW_REG_XCC_ID)" : "=s"(myxcc));
    myxcc &= 15u;
    if (tid == 0)
        __hip_atomic_store(&xf[g * 16 + sl], myxcc + 1u,
                           __ATOMIC_RELAXED, __HIP_MEMORY_SCOPE_AGENT);

    if (tid < 128) {
        int n = (tid >> 5) * 512 + sl * 32 + (tid & 31);
        bias_l[tid] = bih[n] + bhh[n];
        wih_l[tid] = Wih[n];
    }

    const int bT = tid >> 5, jl = tid & 31;               // cell-update mapping
    float c = c0[(g * 16 + bT) * HD + sl * 32 + jl];      // persistent cell state

    const int lane = tid & 63, wv = tid >> 6;
    const int q = lane >> 4, cl = lane & 15;
    const int R = (wv >> 1) * 32 + (wv & 1) * 16;         // wave's 16 gate-rows

    // hoist this lane's 16 B-fragments of Whh into registers (64 VGPRs)
    s16x8 bw[16];
    {
        int r = R + cl;
        int grow = (r >> 5) * 512 + sl * 32 + (r & 31);
        const float* wrow = Whh + (size_t)grow * 512;
        #pragma unroll
        for (int ks = 0; ks < 16; ++ks) {
            s16x8 v;
            #pragma unroll
            for (int j = 0; j < 8; ++j)
                v[j] = (short)f2b(wrow[ks * 32 + q * 8 + j]);
            bw[ks] = v;
        }
    }

    // ---- gather XCC votes; fast iff all 16 wgs report the same XCD
    if (tid < 16) {
        u32 v;
        while ((v = __hip_atomic_load(&xf[g * 16 + tid], __ATOMIC_RELAXED,
                                      __HIP_MEMORY_SCOPE_AGENT)) == 0u)
            __builtin_amdgcn_s_sleep(1);
        u64 bal = __ballot(v == myxcc + 1u);
        if (tid == 0) {
            modesh = ((bal & 0xFFFFull) == 0xFFFFull) ? 0u : 1u;
            toutsh = 0u;
        }
    }

    u32* hlds32 = (u32*)hlds;
    __syncthreads();

    // byte base for this thread's 8 tagged words (+4096 bias for ld8_l2)
    const u64 abase0 = (u64)hb64 + (u64)g * 65536u + (u64)tid * 8u + 4096u;
    // this thread's store slots in the two parity planes (jl even only)
    const int jgl = sl * 32 + jl;
    u64* dpl0 = hb64 + (size_t)(g * 2) * 4096 + bT * 256 + (jgl >> 1);
    u64* dpl1 = dpl0 + 4096;
    u64 wprev = 0ull, wprev2 = 0ull;   // last two stored words (for recovery)

    for (int t = 0; t < TENC; ++t) {
        const u64* src = hb64 + (size_t)(g * 2 + (t & 1)) * 4096;
        const u32 want = (u32)t;
        float xv = xseq[t * BATCH + g * 16 + bT];   // prefetched; used post-MFMA
        u64 vv[8];

        if (modesh == 0u) {
            // ---- FAST: sc0 polls through the shared XCD L2, bounded
            u64 a0 = abase0 + (u64)((t & 1) << 15);
            u64 w0, w1, w2, w3, w4, w5, w6, w7;
            ld8_l2(a0, a0 + 8192u, a0 + 16384u, a0 + 24576u,
                   w0, w1, w2, w3, w4, w5, w6, w7);
            int guard = 2048;
            bool tmo = false;
            for (;;) {
                bool ok = ((u32)(w0 >> 32) == want) & ((u32)(w1 >> 32) == want) &
                          ((u32)(w2 >> 32) == want) & ((u32)(w3 >> 32) == want) &
                          ((u32)(w4 >> 32) == want) & ((u32)(w5 >> 32) == want) &
                          ((u32)(w6 >> 32) == want) & ((u32)(w7 >> 32) == want);
                if (ok) break;
                if (--guard <= 0) { tmo = true; break; }
                ld8_l2(a0, a0 + 8192u, a0 + 16384u, a0 + 24576u,
                       w0, w1, w2, w3, w4, w5, w6, w7);
            }
            vv[0] = w0; vv[1] = w1; vv[2] = w2; vv[3] = w3;
            vv[4] = w4; vv[5] = w5; vv[6] = w6; vv[7] = w7;
            if (tmo) toutsh = 1u;
            __syncthreads();                       // R: collective timeout check
            if (toutsh != 0u) {
                // ---- RECOVERY: everyone republishes last 2 planes agent-scope
                if ((jl & 1) == 0) {
                    if (t >= 1)
                        __hip_atomic_store((t & 1) ? dpl1 : dpl0, wprev,
                                           __ATOMIC_RELAXED, __HIP_MEMORY_SCOPE_AGENT);
                    if (t >= 2)
                        __hip_atomic_store(((t + 1) & 1) ? dpl1 : dpl0, wprev2,
                                           __ATOMIC_RELAXED, __HIP_MEMORY_SCOPE_AGENT);
                }
                if (tid == 0) modesh = 1u;         // slow forever (read post-S1/S2)
                for (;;) {
                    bool ok = true;
                    #pragma unroll
                    for (int i = 0; i < 8; ++i) {
                        if ((u32)(vv[i] >> 32) != want) {
                            ok = false;
                            vv[i] = __hip_atomic_load(src + tid + i * 512,
                                                      __ATOMIC_RELAXED,
                                                      __HIP_MEMORY_SCOPE_AGENT);
                        }
                    }
                    if (ok) break;
                }
            }
        } else {
            // ---- SLOW: proven agent-scope (LLC) path
            #pragma unroll
            for (int i = 0; i < 8; ++i)
                vv[i] = __hip_atomic_load(src + tid + i * 512, __ATOMIC_RELAXED,
                                          __HIP_MEMORY_SCOPE_AGENT);
            for (;;) {
                bool ok = true;
                #pragma unroll
                for (int i = 0; i < 8; ++i) {
                    if ((u32)(vv[i] >> 32) != want) {
                        ok = false;
                        vv[i] = __hip_atomic_load(src + tid + i * 512, __ATOMIC_RELAXED,
                                                  __HIP_MEMORY_SCOPE_AGENT);
                    }
                }
                if (ok) break;
            }
        }

        #pragma unroll
        for (int i = 0; i < 8; ++i) {
            int idx = tid + i * 512;
            hlds32[(idx >> 8) * 260 + (idx & 255)] = (u32)vv[i];
        }
        __syncthreads();                            // S1: hlds ready

        // dual accumulators: halve the dependent MFMA chain
        f32x4 acc0 = {0.f, 0.f, 0.f, 0.f}, acc1 = {0.f, 0.f, 0.f, 0.f};
        #pragma unroll
        for (int ks = 0; ks < 16; ks += 2) {
            s16x8 av0 = *(const s16x8*)&hlds[cl * WPAD + ks * 32 + q * 8];
            s16x8 av1 = *(const s16x8*)&hlds[cl * WPAD + (ks + 1) * 32 + q * 8];
            acc0 = __builtin_amdgcn_mfma_f32_16x16x32_bf16(av0, bw[ks], acc0, 0, 0, 0);
            acc1 = __builtin_amdgcn_mfma_f32_16x16x32_bf16(av1, bw[ks + 1], acc1, 0, 0, 0);
        }
        f32x4 acc = acc0 + acc1;
        #pragma unroll
        for (int r4 = 0; r4 < 4; ++r4)
            exg[(q * 4 + r4) * 132 + R + cl] = acc[r4];   // D: row m=q*4+r4, col n=cl
        __syncthreads();                            // S2: exg ready + hlds reads done

        // LSTM cell for (bT, jl)
        const float* exb = &exg[bT * 132];
        float gi = exb[jl]      + xv * wih_l[jl]      + bias_l[jl];
        float gf = exb[32 + jl] + xv * wih_l[32 + jl] + bias_l[32 + jl];
        float gg = exb[64 + jl] + xv * wih_l[64 + jl] + bias_l[64 + jl];
        float go = exb[96 + jl] + xv * wih_l[96 + jl] + bias_l[96 + jl];
        c = sigm(gf) * c + sigm(gi) * tanh_f(gg);
        float hv = sigm(go) * tanh_f(c);
        u16 h16 = f2b(hv);

        // tagged h_{t+1} store: pair + tag in ONE 8B store (critical path)
        u32 me = (u32)h16;
        u32 up = (u32)__shfl_down((int)me, 1, 64);
        if ((jl & 1) == 0) {
            u64 word = (u64)(me | (up << 16)) | ((u64)(u32)(t + 1) << 32);
            u64* dst = ((t + 1) & 1) ? dpl1 : dpl0;
            if (modesh == 0u)   // sc0: write-through into the shared XCD L2
                st_sc0(dst, word);
            else
                __hip_atomic_store(dst, word, __ATOMIC_RELAXED,
                                   __HIP_MEMORY_SCOPE_AGENT);
            wprev2 = wprev;
            wprev = word;
        }
        // enc write AFTER the handoff store: off the critical path
        enc[((size_t)t * BATCH + g * 16 + bT) * HD + jgl] = h16;
    }
}

// ---------------------------------------------------------------------------
// Fused decoder: one wg per batch row, 32 steps. p2 uses a TRUE 2-deep
// dual-buffer pipeline (2x unrolled blocks, 128B/wave in flight).
// ---------------------------------------------------------------------------
__global__ __launch_bounds__(512, 2) void dec_all(
    const float* __restrict__ xlast, const u16* __restrict__ enc,
    const u16* __restrict__ rT, const float* __restrict__ rWih,
    const float* __restrict__ rbih, const float* __restrict__ rbhh,
    const float* __restrict__ linW, const float* __restrict__ linb,
    float* __restrict__ dout) {

    __shared__ float hp[512];          // h entering the step
    __shared__ float ctxl[8 * 512];    // p1 partials, then p2 ctx partials
    __shared__ float red[512];         // hn broadcast, then reduce slots
    __shared__ float mw[8], lw[8];
    __shared__ float xsh;

    const int tid = threadIdx.x;
    const int b = blockIdx.x;
    const int wv = tid >> 6, lane = tid & 63;

    hp[tid] = b2f(enc[(size_t)511 * BATCH * HD + b * HD + tid]);  // h_enc
    float x = xlast[b];
    const float bia = rbih[tid] + rbhh[tid];
    const float wih = rWih[tid];
    const float lwt = linW[tid];
    const float lb = linb[0];
    const uint4* rT4 = (const uint4*)rT;                 // [512 k][64 chunks]
    const u16* ebase = enc + (size_t)b * HD + lane * 8;  // t-stride = 65536 elems
    __syncthreads();

    for (int s = 0; s < 32; ++s) {
        // preload blocks 0 and 1 (hides under p1)
        uint4 bufA[4], bufB[4];
        #pragma unroll
        for (int i = 0; i < 4; ++i) {
            bufA[i] = *(const uint4*)(ebase + (size_t)(i * 8 + wv) * 65536);
            bufB[i] = *(const uint4*)(ebase + (size_t)(32 + i * 8 + wv) * 65536);
        }

        // ---- phase 1: wave wv covers k in [wv*64, wv*64+64)
        float pa[8] = {0, 0, 0, 0, 0, 0, 0, 0};
        const uint4* base = rT4 + (size_t)(wv * 64) * 64 + lane;
        #pragma unroll 4
        for (int kk = 0; kk < 64; ++kk) {
            float hk = hp[wv * 64 + kk];
            uint4 w = base[kk * 64];
            pa[0] = fmaf(hk, b2f((u16)(w.x & 0xFFFF)), pa[0]);
            pa[1] = fmaf(hk, b2f((u16)(w.x >> 16)),    pa[1]);
            pa[2] = fmaf(hk, b2f((u16)(w.y & 0xFFFF)), pa[2]);
            pa[3] = fmaf(hk, b2f((u16)(w.y >> 16)),    pa[3]);
            pa[4] = fmaf(hk, b2f((u16)(w.z & 0xFFFF)), pa[4]);
            pa[5] = fmaf(hk, b2f((u16)(w.z >> 16)),    pa[5]);
            pa[6] = fmaf(hk, b2f((u16)(w.w & 0xFFFF)), pa[6]);
            pa[7] = fmaf(hk, b2f((u16)(w.w >> 16)),    pa[7]);
        }
        #pragma unroll
        for (int i = 0; i < 8; ++i) ctxl[wv * 512 + lane * 8 + i] = pa[i];
        __syncthreads();

        float a = bia + x * wih;
        #pragma unroll
        for (int i = 0; i < 8; ++i) a += ctxl[i * 512 + tid];
        float hv = tanh_f(a);
        red[tid] = hv;                  // hn broadcast
        __syncthreads();

        // ---- phase 2: wave wv handles t = blk*32 + i*8 + wv
        float h8[8];
        #pragma unroll
        for (int i = 0; i < 8; ++i) h8[i] = red[lane * 8 + i];
        float m = -1e30f, l = 0.f;
        float acc[8] = {0, 0, 0, 0, 0, 0, 0, 0};

        auto proc4 = [&](const uint4* bf) {
            #pragma unroll
            for (int i = 0; i < 4; ++i) {
                uint4 ev = bf[i];
                float e[8];
                e[0] = b2f((u16)(ev.x & 0xFFFF)); e[1] = b2f((u16)(ev.x >> 16));
                e[2] = b2f((u16)(ev.y & 0xFFFF)); e[3] = b2f((u16)(ev.y >> 16));
                e[4] = b2f((u16)(ev.z & 0xFFFF)); e[5] = b2f((u16)(ev.z >> 16));
                e[6] = b2f((u16)(ev.w & 0xFFFF)); e[7] = b2f((u16)(ev.w >> 16));
                float sp = 0.f;
                #pragma unroll
                for (int j = 0; j < 8; ++j) sp = fmaf(e[j], h8[j], sp);
                #pragma unroll
                for (int mk = 1; mk < 64; mk <<= 1) sp += __shfl_xor(sp, mk, 64);
                if (sp > m) {
                    float sc = __expf(m - sp);
                    l *= sc;
                    #pragma unroll
                    for (int j = 0; j < 8; ++j) acc[j] *= sc;
                    m = sp;
                }
                float p = __expf(sp - m);
                l += p;
                #pragma unroll
                for (int j = 0; j < 8; ++j) acc[j] = fmaf(p, e[j], acc[j]);
            }
        };

        for (int bb = 0; bb < 16; bb += 2) {
            uint4 nA[4], nB[4];
            if (bb < 14) {
                #pragma unroll
                for (int i = 0; i < 4; ++i) {
                    nA[i] = *(const uint4*)(ebase +
                              (size_t)((bb + 2) * 32 + i * 8 + wv) * 65536);
                    nB[i] = *(const uint4*)(ebase +
                              (size_t)((bb + 3) * 32 + i * 8 + wv) * 65536);
                }
            }
            proc4(bufA);
            proc4(bufB);
            if (bb < 14) {
                #pragma unroll
                for (int i = 0; i < 4; ++i) { bufA[i] = nA[i]; bufB[i] = nB[i]; }
            }
        }
        if (lane == 0) { mw[wv] = m; lw[wv] = l; }
        #pragma unroll
        for (int i = 0; i < 8; ++i) ctxl[wv * HD + lane * 8 + i] = acc[i];
        __syncthreads();

        // ---- phase 3: merge online-softmax states, project, relu
        float M = mw[0];
        #pragma unroll
        for (int i = 1; i < 8; ++i) M = fmaxf(M, mw[i]);
        float L = 0.f, aw[8];
        #pragma unroll
        for (int i = 0; i < 8; ++i) { aw[i] = __expf(mw[i] - M); L += aw[i] * lw[i]; }
        float cj = 0.f;
        #pragma unroll
        for (int i = 0; i < 8; ++i) cj = fmaf(aw[i], ctxl[i * HD + tid], cj);
        float r = cj * lwt;
        #pragma unroll
        for (int mk = 1; mk < 64; mk <<= 1) r += __shfl_xor(r, mk, 64);
        if (lane == 0) red[wv] = r;
        __syncthreads();
        if (tid == 0) {
            float o = (red[0] + red[1] + red[2] + red[3] +
                       red[4] + red[5] + red[6] + red[7]) / L + lb;
            o = fmaxf(o, 0.f);
            dout[s * BATCH + b] = o;
            xsh = o;
        }
        __syncthreads();
        x = xsh;
        hp[tid] = hv;                   // h for next step
        __syncthreads();
    }
}

// ---------------------------------------------------------------------------
extern "C" void kernel_launch(void* const* d_in, const int* in_sizes, int n_in,
                              void* d_out, int out_size, void* d_ws, size_t ws_size,
                              hipStream_t stream) {
    const float* xseq = (const float*)d_in[0];   // [513,128,1]
    const float* h0   = (const float*)d_in[1];
    const float* c0   = (const float*)d_in[2];
    const float* Wih  = (const float*)d_in[3];   // [2048,1]
    const float* Whh  = (const float*)d_in[4];   // [2048,512]
    const float* bih  = (const float*)d_in[5];
    const float* bhh  = (const float*)d_in[6];
    const float* rWih = (const float*)d_in[7];   // [512,1]
    const float* rWhh = (const float*)d_in[8];   // [512,512]
    const float* rbih = (const float*)d_in[9];
    const float* rbhh = (const float*)d_in[10];
    const float* linW = (const float*)d_in[11];  // [1,512]
    const float* linb = (const float*)d_in[12];
    float* dout = (float*)d_out;                 // [32,128,1]

    // workspace layout
    char* ws = (char*)d_ws;
    u16* enc  = (u16*)ws;                                  // 64 MB
    u16* rT   = (u16*)(ws + 67108864);                     // 512 KB
    u64* hb64 = (u64*)(ws + 67108864 + 524288);            // 512 KB tagged h
    u32* xf   = (u32*)(ws + 67108864 + 1048576);           // 4 KB votes

    init_misc<<<512, 256, 0, stream>>>(h0, rWhh, hb64, rT, xf);
    enc_lstm<<<128, 512, 0, stream>>>(xseq, c0, Wih, Whh, bih, bhh, enc, hb64, xf);
    dec_all<<<128, 512, 0, stream>>>(xseq + 512 * BATCH, enc, rT, rWih,
                                     rbih, rbhh, linW, linb, dout);
}

// Round 6
// 2370.116 us; speedup vs baseline: 623.3720x; 1.3789x over previous
//
#include <hip/hip_runtime.h>
#include <hip/hip_bf16.h>

typedef unsigned short u16;
typedef unsigned int u32;
typedef unsigned long long u64;

#define HD 512
#define BATCH 128
#define TENC 512
#define WPAD 520   // LDS row stride in bf16 elems (even -> u32-aligned rows)

typedef float f32x4 __attribute__((ext_vector_type(4)));
typedef short s16x8 __attribute__((ext_vector_type(8)));

__device__ __forceinline__ u16 f2b(float f) {
    u32 u = __float_as_uint(f);
    u32 r = (u + 0x7FFFu + ((u >> 16) & 1u)) >> 16;   // RNE
    return (u16)r;
}
__device__ __forceinline__ float b2f(u16 h) {
    return __uint_as_float(((u32)h) << 16);
}
__device__ __forceinline__ float sigm(float z) { return 1.0f / (1.0f + __expf(-z)); }
__device__ __forceinline__ float tanh_f(float z) { return 1.0f - 2.0f / (__expf(2.0f * z) + 1.0f); }

// ---------------------------------------------------------------------------
// init: seed tagged h-buffer. Layout: hb64[(g*2+parity)*4096 + b*256 + jp]
//   word = (bf16 h[2jp] | bf16 h[2jp+1]<<16) | ((u64)tag << 32)
// parity0 holds h_0 with tag 0; parity1 zeroed (tag 0, never matches t>=1).
// Also build rnn_Whh transposed bf16 [k][j] for coalesced decoder reads.
// ---------------------------------------------------------------------------
__global__ void init_misc(const float* __restrict__ h0, const float* __restrict__ rWhh,
                          u64* __restrict__ hb64, u16* __restrict__ rT) {
    int idx = blockIdx.x * 256 + threadIdx.x;      // 512 blocks x 256 = 131072
    if (idx < 65536) {                              // 8 g x 2 parity x 4096 words
        int g   = idx >> 13;
        int r   = idx & 8191;
        int p   = r >> 12;
        int ofs = r & 4095;
        int b   = ofs >> 8, jp = ofs & 255;
        u64 v = 0ull;                               // tag 0
        if (p == 0) {
            const float* hrow = h0 + (size_t)(g * 16 + b) * HD + jp * 2;
            u32 lo = (u32)f2b(hrow[0]) | ((u32)f2b(hrow[1]) << 16);
            v = (u64)lo;                            // tag 0 for h_0
        }
        hb64[(size_t)(g * 2 + p) * 4096 + b * 256 + jp] = v;
    }
    for (int i = idx; i < 262144; i += 131072) {    // rT[k*512+j] = rWhh[j][k]
        int k = i >> 9, j = i & 511;
        rT[i] = f2b(rWhh[j * 512 + k]);
    }
}

// ---------------------------------------------------------------------------
// Encoder LSTM: 8 batch-groups x 16 wgs (round-1 proven protocol).
// Cross-wg h handoff via SELF-VALIDATING tagged 64-bit words: {bf16 pair,
// step tag} in one atomic dwordx2 agent-scope store. Readers poll the data
// words until tag==t. Parity-2 buffering (writer of h_{t+1} has consumed all
// of h_t, hence all readers are done with h_{t-1}).
// ---------------------------------------------------------------------------
__global__ __launch_bounds__(512, 2) void enc_lstm(
    const float* __restrict__ xseq, const float* __restrict__ c0,
    const float* __restrict__ Wih, const float* __restrict__ Whh,
    const float* __restrict__ bih, const float* __restrict__ bhh,
    u16* __restrict__ enc, u64* __restrict__ hb64) {

    __shared__ u16 hlds[16 * WPAD];     // 16640 B: staged h tile [16b][512k] bf16
    __shared__ float exg[16 * 132];     // 8448 B: gate pre-activations [b][128 rows]
    __shared__ float bias_l[128];
    __shared__ float wih_l[128];

    const int tid = threadIdx.x;
    const int g = blockIdx.x & 7;       // batch group
    const int sl = blockIdx.x >> 3;     // hidden slot 0..15

    if (tid < 128) {
        int n = (tid >> 5) * 512 + sl * 32 + (tid & 31);
        bias_l[tid] = bih[n] + bhh[n];
        wih_l[tid] = Wih[n];
    }

    const int bT = tid >> 5, jl = tid & 31;               // cell-update mapping
    float c = c0[(g * 16 + bT) * HD + sl * 32 + jl];      // persistent cell state

    const int lane = tid & 63, wv = tid >> 6;
    const int q = lane >> 4, cl = lane & 15;
    const int R = (wv >> 1) * 32 + (wv & 1) * 16;         // wave's 16 gate-rows

    // hoist this lane's 16 B-fragments of Whh into registers (64 VGPRs)
    s16x8 bw[16];
    {
        int r = R + cl;
        int grow = (r >> 5) * 512 + sl * 32 + (r & 31);
        const float* wrow = Whh + (size_t)grow * 512;
        #pragma unroll
        for (int ks = 0; ks < 16; ++ks) {
            s16x8 v;
            #pragma unroll
            for (int j = 0; j < 8; ++j)
                v[j] = (short)f2b(wrow[ks * 32 + q * 8 + j]);
            bw[ks] = v;
        }
    }

    u32* hlds32 = (u32*)hlds;
    __syncthreads();

    const int jgl = sl * 32 + jl;
    u64* dpl0 = hb64 + (size_t)(g * 2) * 4096 + bT * 256 + (jgl >> 1);
    u64* dpl1 = dpl0 + 4096;

    for (int t = 0; t < TENC; ++t) {
        // ---- stage h_t: poll tagged words of buf[t&1] until tag==t
        const u64* src = hb64 + (size_t)(g * 2 + (t & 1)) * 4096;
        const u32 want = (u32)t;
        u64 vv[8];
        #pragma unroll
        for (int i = 0; i < 8; ++i)
            vv[i] = __hip_atomic_load(src + tid + i * 512, __ATOMIC_RELAXED,
                                      __HIP_MEMORY_SCOPE_AGENT);
        float xv = xseq[t * BATCH + g * 16 + bT];   // prefetched; used post-MFMA
        for (;;) {
            bool ok = true;
            #pragma unroll
            for (int i = 0; i < 8; ++i) {
                if ((u32)(vv[i] >> 32) != want) {
                    ok = false;
                    vv[i] = __hip_atomic_load(src + tid + i * 512, __ATOMIC_RELAXED,
                                              __HIP_MEMORY_SCOPE_AGENT);
                }
            }
            if (ok) break;
        }
        #pragma unroll
        for (int i = 0; i < 8; ++i) {
            int idx = tid + i * 512;
            hlds32[(idx >> 8) * 260 + (idx & 255)] = (u32)vv[i];
        }
        __syncthreads();                            // S1: hlds ready

        // dual accumulators: halve the dependent MFMA chain
        f32x4 acc0 = {0.f, 0.f, 0.f, 0.f}, acc1 = {0.f, 0.f, 0.f, 0.f};
        #pragma unroll
        for (int ks = 0; ks < 16; ks += 2) {
            s16x8 av0 = *(const s16x8*)&hlds[cl * WPAD + ks * 32 + q * 8];
            s16x8 av1 = *(const s16x8*)&hlds[cl * WPAD + (ks + 1) * 32 + q * 8];
            acc0 = __builtin_amdgcn_mfma_f32_16x16x32_bf16(av0, bw[ks], acc0, 0, 0, 0);
            acc1 = __builtin_amdgcn_mfma_f32_16x16x32_bf16(av1, bw[ks + 1], acc1, 0, 0, 0);
        }
        f32x4 acc = acc0 + acc1;
        #pragma unroll
        for (int r4 = 0; r4 < 4; ++r4)
            exg[(q * 4 + r4) * 132 + R + cl] = acc[r4];   // D: row m=q*4+r4, col n=cl
        __syncthreads();                            // S2: exg ready + hlds reads done

        // LSTM cell for (bT, jl)
        const float* exb = &exg[bT * 132];
        float gi = exb[jl]      + xv * wih_l[jl]      + bias_l[jl];
        float gf = exb[32 + jl] + xv * wih_l[32 + jl] + bias_l[32 + jl];
        float gg = exb[64 + jl] + xv * wih_l[64 + jl] + bias_l[64 + jl];
        float go = exb[96 + jl] + xv * wih_l[96 + jl] + bias_l[96 + jl];
        c = sigm(gf) * c + sigm(gi) * tanh_f(gg);
        float hv = sigm(go) * tanh_f(c);
        u16 h16 = f2b(hv);

        // tagged h_{t+1} store: pair + tag in ONE atomic 8B store (critical path)
        u32 me = (u32)h16;
        u32 up = (u32)__shfl_down((int)me, 1, 64);
        if ((jl & 1) == 0) {
            u64 word = (u64)(me | (up << 16)) | ((u64)(u32)(t + 1) << 32);
            __hip_atomic_store(((t + 1) & 1) ? dpl1 : dpl0, word,
                               __ATOMIC_RELAXED, __HIP_MEMORY_SCOPE_AGENT);
        }
        // enc write AFTER the handoff store: off the critical path
        enc[((size_t)t * BATCH + g * 16 + bT) * HD + jgl] = h16;
    }
}

// ---------------------------------------------------------------------------
// Fused decoder: one wg per batch row, 32 steps; grid 128 on 256 CUs, so
// each wg owns a CU -> VGPR is free (launch_bounds 512,1).
// p2 RESTRUCTURED: 8 t per iteration. 8 independent dots, then all 8
// butterfly reduces batched (6 dependent stages with 8-way ILP instead of
// 48 dependent stages), ONE online-softmax rescale per 8-t block, e[8][8]
// kept in registers for the ctx update.
// ---------------------------------------------------------------------------
__global__ __launch_bounds__(512, 1) void dec_all(
    const float* __restrict__ xlast, const u16* __restrict__ enc,
    const u16* __restrict__ rT, const float* __restrict__ rWih,
    const float* __restrict__ rbih, const float* __restrict__ rbhh,
    const float* __restrict__ linW, const float* __restrict__ linb,
    float* __restrict__ dout) {

    __shared__ float hp[512];          // h entering the step
    __shared__ float ctxl[8 * 512];    // p1 partials, then p2 ctx partials
    __shared__ float red[512];         // hn broadcast, then reduce slots
    __shared__ float mw[8], lw[8];
    __shared__ float xsh;

    const int tid = threadIdx.x;
    const int b = blockIdx.x;
    const int wv = tid >> 6, lane = tid & 63;

    hp[tid] = b2f(enc[(size_t)511 * BATCH * HD + b * HD + tid]);  // h_enc
    float x = xlast[b];
    const float bia = rbih[tid] + rbhh[tid];
    const float wih = rWih[tid];
    const float lwt = linW[tid];
    const float lb = linb[0];
    const uint4* rT4 = (const uint4*)rT;                 // [512 k][64 chunks]
    const u16* ebase = enc + (size_t)b * HD + lane * 8;  // t-stride = 65536 elems
    __syncthreads();

    for (int s = 0; s < 32; ++s) {
        // ---- phase 1: wave wv covers k in [wv*64, wv*64+64)
        float pa[8] = {0, 0, 0, 0, 0, 0, 0, 0};
        const uint4* base = rT4 + (size_t)(wv * 64) * 64 + lane;
        #pragma unroll 4
        for (int kk = 0; kk < 64; ++kk) {
            float hk = hp[wv * 64 + kk];
            uint4 w = base[kk * 64];
            pa[0] = fmaf(hk, b2f((u16)(w.x & 0xFFFF)), pa[0]);
            pa[1] = fmaf(hk, b2f((u16)(w.x >> 16)),    pa[1]);
            pa[2] = fmaf(hk, b2f((u16)(w.y & 0xFFFF)), pa[2]);
            pa[3] = fmaf(hk, b2f((u16)(w.y >> 16)),    pa[3]);
            pa[4] = fmaf(hk, b2f((u16)(w.z & 0xFFFF)), pa[4]);
            pa[5] = fmaf(hk, b2f((u16)(w.z >> 16)),    pa[5]);
            pa[6] = fmaf(hk, b2f((u16)(w.w & 0xFFFF)), pa[6]);
            pa[7] = fmaf(hk, b2f((u16)(w.w >> 16)),    pa[7]);
        }
        #pragma unroll
        for (int i = 0; i < 8; ++i) ctxl[wv * 512 + lane * 8 + i] = pa[i];
        __syncthreads();

        float a = bia + x * wih;
        #pragma unroll
        for (int i = 0; i < 8; ++i) a += ctxl[i * 512 + tid];
        float hv = tanh_f(a);
        red[tid] = hv;                  // hn broadcast
        __syncthreads();

        // ---- phase 2: wave wv handles t = it*64 + i*8 + wv, 8 t per iter
        float h8[8];
        #pragma unroll
        for (int i = 0; i < 8; ++i) h8[i] = red[lane * 8 + i];
        float m = -1e30f, l = 0.f;
        float acc[8] = {0, 0, 0, 0, 0, 0, 0, 0};

        uint4 buf[8];
        #pragma unroll
        for (int i = 0; i < 8; ++i)
            buf[i] = *(const uint4*)(ebase + (size_t)(i * 8 + wv) * 65536);

        for (int it = 0; it < 8; ++it) {
            uint4 nxt[8];
            if (it < 7) {
                #pragma unroll
                for (int i = 0; i < 8; ++i)
                    nxt[i] = *(const uint4*)(ebase +
                               (size_t)((it + 1) * 64 + i * 8 + wv) * 65536);
            }
            float e[8][8], sp[8];
            #pragma unroll
            for (int i = 0; i < 8; ++i) {
                uint4 ev = buf[i];
                e[i][0] = b2f((u16)(ev.x & 0xFFFF)); e[i][1] = b2f((u16)(ev.x >> 16));
                e[i][2] = b2f((u16)(ev.y & 0xFFFF)); e[i][3] = b2f((u16)(ev.y >> 16));
                e[i][4] = b2f((u16)(ev.z & 0xFFFF)); e[i][5] = b2f((u16)(ev.z >> 16));
                e[i][6] = b2f((u16)(ev.w & 0xFFFF)); e[i][7] = b2f((u16)(ev.w >> 16));
                float sd = 0.f;
                #pragma unroll
                for (int j = 0; j < 8; ++j) sd = fmaf(e[i][j], h8[j], sd);
                sp[i] = sd;
            }
            // batched butterfly: 6 dependent stages, 8-way ILP
            #pragma unroll
            for (int mk = 1; mk < 64; mk <<= 1) {
                #pragma unroll
                for (int i = 0; i < 8; ++i) sp[i] += __shfl_xor(sp[i], mk, 64);
            }
            float pm = sp[0];
            #pragma unroll
            for (int i = 1; i < 8; ++i) pm = fmaxf(pm, sp[i]);
            if (pm > m) {                           // one rescale per 8-t block
                float sc = __expf(m - pm);
                l *= sc;
                #pragma unroll
                for (int j = 0; j < 8; ++j) acc[j] *= sc;
                m = pm;
            }
            #pragma unroll
            for (int i = 0; i < 8; ++i) {
                float p = __expf(sp[i] - m);
                l += p;
                #pragma unroll
                for (int j = 0; j < 8; ++j) acc[j] = fmaf(p, e[i][j], acc[j]);
            }
            if (it < 7) {
                #pragma unroll
                for (int i = 0; i < 8; ++i) buf[i] = nxt[i];
            }
        }
        if (lane == 0) { mw[wv] = m; lw[wv] = l; }
        #pragma unroll
        for (int i = 0; i < 8; ++i) ctxl[wv * HD + lane * 8 + i] = acc[i];
        __syncthreads();

        // ---- phase 3: merge online-softmax states, project, relu
        float M = mw[0];
        #pragma unroll
        for (int i = 1; i < 8; ++i) M = fmaxf(M, mw[i]);
        float L = 0.f, aw[8];
        #pragma unroll
        for (int i = 0; i < 8; ++i) { aw[i] = __expf(mw[i] - M); L += aw[i] * lw[i]; }
        float cj = 0.f;
        #pragma unroll
        for (int i = 0; i < 8; ++i) cj = fmaf(aw[i], ctxl[i * HD + tid], cj);
        float r = cj * lwt;
        #pragma unroll
        for (int mk = 1; mk < 64; mk <<= 1) r += __shfl_xor(r, mk, 64);
        if (lane == 0) red[wv] = r;
        __syncthreads();
        if (tid == 0) {
            float o = (red[0] + red[1] + red[2] + red[3] +
                       red[4] + red[5] + red[6] + red[7]) / L + lb;
            o = fmaxf(o, 0.f);
            dout[s * BATCH + b] = o;
            xsh = o;
        }
        __syncthreads();
        x = xsh;
        hp[tid] = hv;                   // h for next step
        __syncthreads();
    }
}

// ---------------------------------------------------------------------------
extern "C" void kernel_launch(void* const* d_in, const int* in_sizes, int n_in,
                              void* d_out, int out_size, void* d_ws, size_t ws_size,
                              hipStream_t stream) {
    const float* xseq = (const float*)d_in[0];   // [513,128,1]
    const float* h0   = (const float*)d_in[1];
    const float* c0   = (const float*)d_in[2];
    const float* Wih  = (const float*)d_in[3];   // [2048,1]
    const float* Whh  = (const float*)d_in[4];   // [2048,512]
    const float* bih  = (const float*)d_in[5];
    const float* bhh  = (const float*)d_in[6];
    const float* rWih = (const float*)d_in[7];   // [512,1]
    const float* rWhh = (const float*)d_in[8];   // [512,512]
    const float* rbih = (const float*)d_in[9];
    const float* rbhh = (const float*)d_in[10];
    const float* linW = (const float*)d_in[11];  // [1,512]
    const float* linb = (const float*)d_in[12];
    float* dout = (float*)d_out;                 // [32,128,1]

    // workspace layout
    char* ws = (char*)d_ws;
    u16* enc  = (u16*)ws;                                  // 64 MB
    u16* rT   = (u16*)(ws + 67108864);                     // 512 KB
    u64* hb64 = (u64*)(ws + 67108864 + 524288);            // 512 KB tagged h

    init_misc<<<512, 256, 0, stream>>>(h0, rWhh, hb64, rT);
    enc_lstm<<<128, 512, 0, stream>>>(xseq, c0, Wih, Whh, bih, bhh, enc, hb64);
    dec_all<<<128, 512, 0, stream>>>(xseq + 512 * BATCH, enc, rT, rWih,
                                     rbih, rbhh, linW, linb, dout);
}